// Round 2
// baseline (661.755 us; speedup 1.0000x reference)
//
#include <hip/hip_runtime.h>
#include <hip/hip_cooperative_groups.h>

namespace cg = cooperative_groups;

// Complex Daubechies wavelet forward decomposition, 6 levels, fused into one
// cooperative kernel (grid.sync between levels). images [8,3,1024,1024] f32
// -> out [8,3,2,1024,1024] f32.
//
// Per level: vertical complex 6-tap circular conv (stride-2, lo|hi stacked
// along H), then horizontal ditto along W. Level i+1 consumes level i's LL
// quadrant, which we ping-pong through d_ws (the LL written to d_out by
// levels 0..4 is dead — overwritten by the next level — so we skip it).
//
// Block = 256 threads; each "unit" = (bc, group of PPB row-pairs). PPB scales
// up at small levels so all threads stay busy (L5: 16 pairs/block = whole
// plane). LDS rows are halo-padded (+4 left, +4 right) so the horizontal
// taps need no wrap masking.

#define FULL_W 1024
#define BC_TOTAL 24
#define SMAX 1040   // max PPB*(W+8) = 1*(1024+8)

struct Filt { float lor[6], loi[6], hir[6], hii[6]; };

__device__ __forceinline__ void load_filters(const float* __restrict__ lo_pass,
                                             const float* __restrict__ hi_pass,
                                             Filt& f) {
    const float sc = 0.70710678118654752440f;  // 2^-0.5
#pragma unroll
    for (int t = 0; t < 6; ++t) {
        f.lor[t] = lo_pass[t]     * sc;
        f.loi[t] = lo_pass[6 + t] * sc;
        f.hir[t] = hi_pass[t]     * sc;
        f.hii[t] = hi_pass[6 + t] * sc;
    }
}

template<int PPB, int W, bool HAS_IM, bool LAST>
__device__ __forceinline__ void run_level(const float* __restrict__ src,
                                          float* __restrict__ dst,
                                          float* __restrict__ ll_out,
                                          const Filt& f,
                                          float* __restrict__ s_lr,
                                          float* __restrict__ s_li,
                                          float* __restrict__ s_hr,
                                          float* __restrict__ s_hi)
{
    constexpr int H    = W;
    constexpr int W2   = W / 2;
    constexpr int H2   = H / 2;
    constexpr int SSTR = W + 8;        // LDS row stride; interior at +4
    constexpr int NV   = W / 4;        // float4 columns per pair
    constexpr int GRPS = H2 / PPB;     // pair-groups per bc plane
    constexpr int UNITS = BC_TOTAL * GRPS;
    const int tid = threadIdx.x;

    for (int u = blockIdx.x; u < UNITS; u += gridDim.x) {
        const int bc = u / GRPS;
        const int g0 = (u % GRPS) * PPB;   // first row-pair of this unit
        const float* srcRe = src + (size_t)bc * (HAS_IM ? 2 : 1) * H * W;

        // ---- phase 1: vertical complex conv -> LDS (4 planes) ----
        if (tid < PPB * NV) {
            const int p  = tid / NV;
            const int cv = tid - p * NV;
            const int j  = g0 + p;
            float alr[4] = {0.f,0.f,0.f,0.f};
            float ali[4] = {0.f,0.f,0.f,0.f};
            float ahr[4] = {0.f,0.f,0.f,0.f};
            float ahi[4] = {0.f,0.f,0.f,0.f};
#pragma unroll
            for (int t = 0; t < 6; ++t) {
                const int y = (2*j - 3 + t + H) & (H - 1);   // circular pad 3
                const float4 rv = *reinterpret_cast<const float4*>(srcRe + (size_t)y*W + 4*cv);
                const float rr[4] = {rv.x, rv.y, rv.z, rv.w};
#pragma unroll
                for (int k = 0; k < 4; ++k) {
                    alr[k] = fmaf(rr[k], f.lor[t], alr[k]);
                    ali[k] = fmaf(rr[k], f.loi[t], ali[k]);
                    ahr[k] = fmaf(rr[k], f.hir[t], ahr[k]);
                    ahi[k] = fmaf(rr[k], f.hii[t], ahi[k]);
                }
                if constexpr (HAS_IM) {
                    const float4 iv = *reinterpret_cast<const float4*>(
                        srcRe + (size_t)H*W + (size_t)y*W + 4*cv);
                    const float ii[4] = {iv.x, iv.y, iv.z, iv.w};
#pragma unroll
                    for (int k = 0; k < 4; ++k) {
                        alr[k] = fmaf(-ii[k], f.loi[t], alr[k]);
                        ali[k] = fmaf( ii[k], f.lor[t], ali[k]);
                        ahr[k] = fmaf(-ii[k], f.hii[t], ahr[k]);
                        ahi[k] = fmaf( ii[k], f.hir[t], ahi[k]);
                    }
                }
            }
            const int o = p*SSTR + 4 + 4*cv;
            *reinterpret_cast<float4*>(s_lr + o) = make_float4(alr[0],alr[1],alr[2],alr[3]);
            *reinterpret_cast<float4*>(s_li + o) = make_float4(ali[0],ali[1],ali[2],ali[3]);
            *reinterpret_cast<float4*>(s_hr + o) = make_float4(ahr[0],ahr[1],ahr[2],ahr[3]);
            *reinterpret_cast<float4*>(s_hi + o) = make_float4(ahi[0],ahi[1],ahi[2],ahi[3]);
        }
        __syncthreads();

        // ---- halo: replicate 3 wrap columns on each side ----
        if (tid < PPB * 3) {
            const int p = tid / 3, k = tid - p * 3, b = p * SSTR;
            s_lr[b+1+k] = s_lr[b+4+W-3+k];   s_lr[b+4+W+k] = s_lr[b+4+k];
            s_li[b+1+k] = s_li[b+4+W-3+k];   s_li[b+4+W+k] = s_li[b+4+k];
            s_hr[b+1+k] = s_hr[b+4+W-3+k];   s_hr[b+4+W+k] = s_hr[b+4+k];
            s_hi[b+1+k] = s_hi[b+4+W-3+k];   s_hi[b+4+W+k] = s_hi[b+4+k];
        }
        __syncthreads();

        // ---- phase 2: horizontal complex conv from LDS, store ----
        float* dstRe = dst + (size_t)(bc*2) * FULL_W * FULL_W;
        float* dstIm = dstRe + (size_t)FULL_W * FULL_W;
        for (int qq = tid; qq < PPB * W2; qq += 256) {
            const int p = qq / W2;
            const int q = qq - p * W2;
            const int j = g0 + p;
            const int bi = p*SSTR + 1 + 2*q;   // = base of taps (col 2q-3)
            float c1=0.f,c2=0.f,c3=0.f,c4=0.f,c5=0.f,c6=0.f,c7=0.f,c8=0.f;
            float d1=0.f,d2=0.f,d3=0.f,d4=0.f,d5=0.f,d6=0.f,d7=0.f,d8=0.f;
#pragma unroll
            for (int t = 0; t < 6; ++t) {
                const float vlr = s_lr[bi+t], vli = s_li[bi+t];
                const float vhr = s_hr[bi+t], vhi = s_hi[bi+t];
                c1 = fmaf(vlr, f.lor[t], c1);  c2 = fmaf(vli, f.loi[t], c2);
                c3 = fmaf(vlr, f.loi[t], c3);  c4 = fmaf(vli, f.lor[t], c4);
                c5 = fmaf(vlr, f.hir[t], c5);  c6 = fmaf(vli, f.hii[t], c6);
                c7 = fmaf(vlr, f.hii[t], c7);  c8 = fmaf(vli, f.hir[t], c8);
                d1 = fmaf(vhr, f.lor[t], d1);  d2 = fmaf(vhi, f.loi[t], d2);
                d3 = fmaf(vhr, f.loi[t], d3);  d4 = fmaf(vhi, f.lor[t], d4);
                d5 = fmaf(vhr, f.hir[t], d5);  d6 = fmaf(vhi, f.hii[t], d6);
                d7 = fmaf(vhr, f.hii[t], d7);  d8 = fmaf(vhi, f.hir[t], d8);
            }
            const float oRe0 = c1 - c2;
            const float oIm0 = c3 + c4;
            const int   j2   = j + H2;
            // detail quadrants: write-once, never re-read -> nontemporal
            __builtin_nontemporal_store(c5 - c6, dstRe + (size_t)j  * FULL_W + W2 + q);
            __builtin_nontemporal_store(c7 + c8, dstIm + (size_t)j  * FULL_W + W2 + q);
            __builtin_nontemporal_store(d1 - d2, dstRe + (size_t)j2 * FULL_W + q);
            __builtin_nontemporal_store(d5 - d6, dstRe + (size_t)j2 * FULL_W + W2 + q);
            __builtin_nontemporal_store(d3 + d4, dstIm + (size_t)j2 * FULL_W + q);
            __builtin_nontemporal_store(d7 + d8, dstIm + (size_t)j2 * FULL_W + W2 + q);
            if constexpr (LAST) {
                __builtin_nontemporal_store(oRe0, dstRe + (size_t)j * FULL_W + q);
                __builtin_nontemporal_store(oIm0, dstIm + (size_t)j * FULL_W + q);
            } else {
                // LL -> workspace only (the dst copy would be dead data)
                float* llRe = ll_out + (size_t)bc * 2 * H2 * W2;
                llRe[(size_t)j * W2 + q]                   = oRe0;
                llRe[(size_t)H2 * W2 + (size_t)j * W2 + q] = oIm0;
            }
        }
        __syncthreads();   // LDS reused by next unit
    }
}

__global__ __launch_bounds__(256)
void wavelet_all(const float* __restrict__ images, const float* __restrict__ lo_pass,
                 const float* __restrict__ hi_pass, float* __restrict__ out,
                 float* __restrict__ bufA, float* __restrict__ bufB)
{
    __shared__ float s_lr[SMAX], s_li[SMAX], s_hr[SMAX], s_hi[SMAX];
    Filt f;
    load_filters(lo_pass, hi_pass, f);
    cg::grid_group grid = cg::this_grid();

    run_level<1,1024,false,false>(images, out, bufA, f, s_lr,s_li,s_hr,s_hi);
    __threadfence(); grid.sync();
    run_level<1, 512,true ,false>(bufA,   out, bufB, f, s_lr,s_li,s_hr,s_hi);
    __threadfence(); grid.sync();
    run_level<2, 256,true ,false>(bufB,   out, bufA, f, s_lr,s_li,s_hr,s_hi);
    __threadfence(); grid.sync();
    run_level<4, 128,true ,false>(bufA,   out, bufB, f, s_lr,s_li,s_hr,s_hi);
    __threadfence(); grid.sync();
    run_level<8,  64,true ,false>(bufB,   out, bufA, f, s_lr,s_li,s_hr,s_hi);
    __threadfence(); grid.sync();
    run_level<16, 32,true ,true >(bufA,   out, nullptr, f, s_lr,s_li,s_hr,s_hi);
}

// ---- fallback: plain per-level launches (if cooperative launch fails) ----
template<int PPB, int W, bool HAS_IM, bool LAST>
__global__ __launch_bounds__(256)
void wavelet_one(const float* __restrict__ src, const float* __restrict__ lo_pass,
                 const float* __restrict__ hi_pass, float* __restrict__ dst,
                 float* __restrict__ ll)
{
    __shared__ float s_lr[PPB*(W+8)], s_li[PPB*(W+8)], s_hr[PPB*(W+8)], s_hi[PPB*(W+8)];
    Filt f;
    load_filters(lo_pass, hi_pass, f);
    run_level<PPB,W,HAS_IM,LAST>(src, dst, ll, f, s_lr,s_li,s_hr,s_hi);
}

extern "C" void kernel_launch(void* const* d_in, const int* in_sizes, int n_in,
                              void* d_out, int out_size, void* d_ws, size_t ws_size,
                              hipStream_t stream)
{
    const float* images = (const float*)d_in[0];
    const float* lo     = (const float*)d_in[1];
    const float* hi     = (const float*)d_in[2];
    float* out  = (float*)d_out;
    float* bufA = (float*)d_ws;                              // 512^2 LL (50.3 MB)
    float* bufB = bufA + (size_t)BC_TOTAL * 2 * 512 * 512;   // 256^2 LL (12.6 MB)

    int dev = 0;
    hipGetDevice(&dev);
    int cus = 0;
    hipDeviceGetAttribute(&cus, hipDeviceAttributeMultiprocessorCount, dev);
    if (cus <= 0) cus = 256;
    int nb = 0;
    hipError_t oe = hipOccupancyMaxActiveBlocksPerMultiprocessor(&nb, wavelet_all, 256, 0);
    if (oe != hipSuccess || nb <= 0) nb = 2;
    int grid = cus * nb;
    if (grid > 12288) grid = 12288;

    void* args[] = {(void*)&images, (void*)&lo, (void*)&hi,
                    (void*)&out, (void*)&bufA, (void*)&bufB};
    hipError_t le = hipLaunchCooperativeKernel((void*)wavelet_all, dim3(grid), dim3(256),
                                               args, 0, stream);
    if (le != hipSuccess) {
        wavelet_one<1,1024,false,false><<<dim3(12288), dim3(256), 0, stream>>>(images, lo, hi, out, bufA);
        wavelet_one<1, 512,true ,false><<<dim3( 6144), dim3(256), 0, stream>>>(bufA,   lo, hi, out, bufB);
        wavelet_one<2, 256,true ,false><<<dim3( 1536), dim3(256), 0, stream>>>(bufB,   lo, hi, out, bufA);
        wavelet_one<4, 128,true ,false><<<dim3(  384), dim3(256), 0, stream>>>(bufA,   lo, hi, out, bufB);
        wavelet_one<8,  64,true ,false><<<dim3(   96), dim3(256), 0, stream>>>(bufB,   lo, hi, out, bufA);
        wavelet_one<16, 32,true ,true ><<<dim3(   24), dim3(256), 0, stream>>>(bufA,   lo, hi, out, nullptr);
    }
}

// Round 3
// 316.088 us; speedup vs baseline: 2.0936x; 2.0936x over previous
//
#include <hip/hip_runtime.h>

// Complex Daubechies wavelet forward decomposition, 6 levels.
// images [8,3,1024,1024] f32 -> out [8,3,2,1024,1024] f32.
//
// Round-3 structure: back to one plain launch per level (round-1's massive
// TLP — the round-2 cooperative fusion was latency-bound at 7% HBM).
// Kept/added:
//  - dead-write elim: LL quadrant of levels 0..4 goes ONLY to the d_ws
//    ping-pong (the d_out copy is overwritten by the next level anyway)
//  - PPB row-pairs per block so all levels keep 256 threads busy
//  - XCD-chunked block swizzle: adjacent j (sharing 4/6 source rows) land
//    on the same XCD's L2 instead of round-robining across XCDs
//  - halo-padded LDS rows: no wrap masking in the horizontal tap loop
//  - nontemporal stores for detail quadrants (write-once, never re-read)

#define BC_TOTAL 24
#define FULL_W 1024

struct Filt { float lor[6], loi[6], hir[6], hii[6]; };

__device__ __forceinline__ void load_filters(const float* __restrict__ lo_pass,
                                             const float* __restrict__ hi_pass,
                                             Filt& f) {
    const float sc = 0.70710678118654752440f;  // 2^-0.5
#pragma unroll
    for (int t = 0; t < 6; ++t) {
        f.lor[t] = lo_pass[t]     * sc;
        f.loi[t] = lo_pass[6 + t] * sc;
        f.hir[t] = hi_pass[t]     * sc;
        f.hii[t] = hi_pass[6 + t] * sc;
    }
}

template<int W, int PPB, bool HAS_IM, bool LAST>
__global__ __launch_bounds__(256)
void wavelet_one(const float* __restrict__ src,
                 const float* __restrict__ lo_pass,
                 const float* __restrict__ hi_pass,
                 float* __restrict__ dst,
                 float* __restrict__ ll_out)
{
    constexpr int H    = W;
    constexpr int W2   = W / 2;
    constexpr int H2   = H / 2;
    constexpr int SSTR = W + 8;          // LDS row stride; interior at +4
    constexpr int NV   = W / 4;          // float4 columns per row-pair
    constexpr int GRPS = H2 / PPB;       // units per bc plane
    constexpr int UNITS = BC_TOTAL * GRPS;
    static_assert(UNITS % 8 == 0, "swizzle needs UNITS % 8 == 0");
    constexpr int CHUNK = UNITS / 8;

    __shared__ float s_lr[PPB * SSTR], s_li[PPB * SSTR];
    __shared__ float s_hr[PPB * SSTR], s_hi[PPB * SSTR];

    Filt f;
    load_filters(lo_pass, hi_pass, f);

    // XCD-chunked swizzle (bijective: UNITS % 8 == 0). Consecutive units
    // (same bc, adjacent j-groups) stay on one XCD -> L2 reuse of the
    // 4-row tap overlap between neighboring row-pairs.
    const int bid = blockIdx.x;
    const int u   = (bid & 7) * CHUNK + (bid >> 3);
    const int bc  = u / GRPS;
    const int g0  = (u - bc * GRPS) * PPB;   // first row-pair of this unit

    const int tid = threadIdx.x;
    const float* srcRe = src + (size_t)bc * (HAS_IM ? 2 : 1) * H * W;

    // ---- phase 1: vertical complex conv -> LDS (4 planes) ----
    if (tid < PPB * NV) {
        const int p  = tid / NV;
        const int cv = tid - p * NV;
        const int j  = g0 + p;
        float alr[4] = {0.f,0.f,0.f,0.f};
        float ali[4] = {0.f,0.f,0.f,0.f};
        float ahr[4] = {0.f,0.f,0.f,0.f};
        float ahi[4] = {0.f,0.f,0.f,0.f};
#pragma unroll
        for (int t = 0; t < 6; ++t) {
            const int y = (2*j - 3 + t + H) & (H - 1);   // circular pad 3
            const float4 rv = *reinterpret_cast<const float4*>(srcRe + (size_t)y*W + 4*cv);
            const float rr[4] = {rv.x, rv.y, rv.z, rv.w};
#pragma unroll
            for (int k = 0; k < 4; ++k) {
                alr[k] = fmaf(rr[k], f.lor[t], alr[k]);
                ali[k] = fmaf(rr[k], f.loi[t], ali[k]);
                ahr[k] = fmaf(rr[k], f.hir[t], ahr[k]);
                ahi[k] = fmaf(rr[k], f.hii[t], ahi[k]);
            }
            if constexpr (HAS_IM) {
                const float4 iv = *reinterpret_cast<const float4*>(
                    srcRe + (size_t)H*W + (size_t)y*W + 4*cv);
                const float ii[4] = {iv.x, iv.y, iv.z, iv.w};
#pragma unroll
                for (int k = 0; k < 4; ++k) {
                    alr[k] = fmaf(-ii[k], f.loi[t], alr[k]);
                    ali[k] = fmaf( ii[k], f.lor[t], ali[k]);
                    ahr[k] = fmaf(-ii[k], f.hii[t], ahr[k]);
                    ahi[k] = fmaf( ii[k], f.hir[t], ahi[k]);
                }
            }
        }
        const int o = p*SSTR + 4 + 4*cv;
        *reinterpret_cast<float4*>(s_lr + o) = make_float4(alr[0],alr[1],alr[2],alr[3]);
        *reinterpret_cast<float4*>(s_li + o) = make_float4(ali[0],ali[1],ali[2],ali[3]);
        *reinterpret_cast<float4*>(s_hr + o) = make_float4(ahr[0],ahr[1],ahr[2],ahr[3]);
        *reinterpret_cast<float4*>(s_hi + o) = make_float4(ahi[0],ahi[1],ahi[2],ahi[3]);
    }
    __syncthreads();

    // ---- halo: replicate 3 wrap columns each side ----
    if (tid < PPB * 3) {
        const int p = tid / 3, k = tid - p * 3, b = p * SSTR;
        s_lr[b+1+k] = s_lr[b+4+W-3+k];   s_lr[b+4+W+k] = s_lr[b+4+k];
        s_li[b+1+k] = s_li[b+4+W-3+k];   s_li[b+4+W+k] = s_li[b+4+k];
        s_hr[b+1+k] = s_hr[b+4+W-3+k];   s_hr[b+4+W+k] = s_hr[b+4+k];
        s_hi[b+1+k] = s_hi[b+4+W-3+k];   s_hi[b+4+W+k] = s_hi[b+4+k];
    }
    __syncthreads();

    // ---- phase 2: horizontal complex conv from LDS, store ----
    float* dstRe = dst + (size_t)(bc*2) * FULL_W * FULL_W;
    float* dstIm = dstRe + (size_t)FULL_W * FULL_W;
    for (int tt = tid; tt < PPB * W2; tt += 256) {
        const int p = tt / W2;
        const int q = tt - p * W2;
        const int j = g0 + p;
        const int bi = p*SSTR + 1 + 2*q;   // tap base (col 2q-3)
        float c1=0.f,c2=0.f,c3=0.f,c4=0.f,c5=0.f,c6=0.f,c7=0.f,c8=0.f;
        float d1=0.f,d2=0.f,d3=0.f,d4=0.f,d5=0.f,d6=0.f,d7=0.f,d8=0.f;
#pragma unroll
        for (int t = 0; t < 6; ++t) {
            const float vlr = s_lr[bi+t], vli = s_li[bi+t];
            const float vhr = s_hr[bi+t], vhi = s_hi[bi+t];
            c1 = fmaf(vlr, f.lor[t], c1);  c2 = fmaf(vli, f.loi[t], c2);
            c3 = fmaf(vlr, f.loi[t], c3);  c4 = fmaf(vli, f.lor[t], c4);
            c5 = fmaf(vlr, f.hir[t], c5);  c6 = fmaf(vli, f.hii[t], c6);
            c7 = fmaf(vlr, f.hii[t], c7);  c8 = fmaf(vli, f.hir[t], c8);
            d1 = fmaf(vhr, f.lor[t], d1);  d2 = fmaf(vhi, f.loi[t], d2);
            d3 = fmaf(vhr, f.loi[t], d3);  d4 = fmaf(vhi, f.lor[t], d4);
            d5 = fmaf(vhr, f.hir[t], d5);  d6 = fmaf(vhi, f.hii[t], d6);
            d7 = fmaf(vhr, f.hii[t], d7);  d8 = fmaf(vhi, f.hir[t], d8);
        }
        const float oRe0 = c1 - c2;
        const float oIm0 = c3 + c4;
        const int   j2   = j + H2;
        // detail quadrants: write-once, never re-read -> nontemporal
        __builtin_nontemporal_store(c5 - c6, dstRe + (size_t)j  * FULL_W + W2 + q);
        __builtin_nontemporal_store(c7 + c8, dstIm + (size_t)j  * FULL_W + W2 + q);
        __builtin_nontemporal_store(d1 - d2, dstRe + (size_t)j2 * FULL_W + q);
        __builtin_nontemporal_store(d5 - d6, dstRe + (size_t)j2 * FULL_W + W2 + q);
        __builtin_nontemporal_store(d3 + d4, dstIm + (size_t)j2 * FULL_W + q);
        __builtin_nontemporal_store(d7 + d8, dstIm + (size_t)j2 * FULL_W + W2 + q);
        if constexpr (LAST) {
            __builtin_nontemporal_store(oRe0, dstRe + (size_t)j * FULL_W + q);
            __builtin_nontemporal_store(oIm0, dstIm + (size_t)j * FULL_W + q);
        } else {
            // LL only to workspace (dst copy would be dead); keep cacheable
            float* llRe = ll_out + (size_t)bc * 2 * H2 * W2;
            llRe[(size_t)j * W2 + q]                   = oRe0;
            llRe[(size_t)H2 * W2 + (size_t)j * W2 + q] = oIm0;
        }
    }
}

extern "C" void kernel_launch(void* const* d_in, const int* in_sizes, int n_in,
                              void* d_out, int out_size, void* d_ws, size_t ws_size,
                              hipStream_t stream)
{
    const float* images = (const float*)d_in[0];
    const float* lo     = (const float*)d_in[1];
    const float* hi     = (const float*)d_in[2];
    float* out  = (float*)d_out;
    float* bufA = (float*)d_ws;                              // 512^2 LL (50.3 MB)
    float* bufB = bufA + (size_t)BC_TOTAL * 2 * 512 * 512;   // 256^2 LL (12.6 MB)

    const dim3 blk(256);
    wavelet_one<1024, 1,false,false><<<dim3(12288), blk, 0, stream>>>(images, lo, hi, out, bufA);
    wavelet_one< 512, 2,true ,false><<<dim3( 3072), blk, 0, stream>>>(bufA,   lo, hi, out, bufB);
    wavelet_one< 256, 4,true ,false><<<dim3(  768), blk, 0, stream>>>(bufB,   lo, hi, out, bufA);
    wavelet_one< 128, 8,true ,false><<<dim3(  192), blk, 0, stream>>>(bufA,   lo, hi, out, bufB);
    wavelet_one<  64,16,true ,false><<<dim3(   48), blk, 0, stream>>>(bufB,   lo, hi, out, bufA);
    wavelet_one<  32,16,true ,true ><<<dim3(   24), blk, 0, stream>>>(bufA,   lo, hi, out, nullptr);
}